// Round 6
// baseline (7828.162 us; speedup 1.0000x reference)
//
#include <hip/hip_runtime.h>

// LSTM B=64, S=512, D=H=1024 on MI355X (gfx950).
// R9: R8 structure UNCHANGED + (a) real FMA power-burn in all spin loops
// (4 independent v_fma chains -> saturates SIMD issue; tests DVFS theory
// directly) + (b) WRITE_SIZE-encoded wait-fraction probe: block0/wave8
// measures s_memtime cycles spent in the slot-poll wait vs total loop
// cycles; after the loop writes 2MB marker + 0.25MB * floor(frac*64) of
// distinct nt lines into spare workspace. Readout: WRITE_SIZE delta vs
// 239.29 MB baseline -> frac64 = (delta_MB - 2) / 0.25.
// 2 recurrence groups (32 batches) x 64 j-slices = 128 blocks x 1024 thr.
// Full K=2048 weights in VGPRs (16 waves = 4 K-quarters x 4 row-groups).

typedef short short8 __attribute__((ext_vector_type(8)));
typedef float float4v __attribute__((ext_vector_type(4)));
typedef int int4v __attribute__((ext_vector_type(4)));
typedef unsigned long long u64;

__device__ __forceinline__ short f2bf(float f) {
  union { float f; unsigned u; } v; v.f = f;
  unsigned r = (v.u + 0x7fffu + ((v.u >> 16) & 1u)) >> 16;  // RNE
  return (short)r;
}

__device__ __forceinline__ float sigm(float z) {
  float e = __expf(-fabsf(z));
  float p = 1.0f / (1.0f + e);
  return z >= 0.0f ? p : 1.0f - p;
}

__device__ __forceinline__ float tanh_s(float z) {
  float e = __expf(-2.0f * fabsf(z));
  float r = (1.0f - e) / (1.0f + e);
  return z >= 0.0f ? r : -r;
}

__device__ __forceinline__ u64 memtime() {
  u64 t;
  asm volatile("s_memtime %0\ns_waitcnt lgkmcnt(0)" : "=s"(t));
  return t;
}

// 64 independent FMAs (4 chains) -- saturates VALU issue for ~70 cycles.
__device__ __forceinline__ void burn(float* a) {
  #pragma unroll
  for (int i = 0; i < 16; ++i) {
    a[0] = __builtin_fmaf(a[0], 1.0000001f, 1.0f);
    a[1] = __builtin_fmaf(a[1], 1.0000002f, 1.0f);
    a[2] = __builtin_fmaf(a[2], 1.0000003f, 1.0f);
    a[3] = __builtin_fmaf(a[3], 1.0000004f, 1.0f);
  }
}

// one-time x fp32 [b][s][d] -> bf16 [s][b][d]
__global__ __launch_bounds__(256) void xconv(const float* __restrict__ x,
                                             short* __restrict__ xbf) {
  const int gid = blockIdx.x * 256 + threadIdx.x;
  const long i8 = (long)gid * 8;
  const int d  = (int)(i8 & 1023);
  const int bs = (int)(i8 >> 10);
  const int s  = bs & 511;
  const int b  = bs >> 9;
  const float4v* src = (const float4v*)(x + i8);
  float4v v0 = src[0], v1 = src[1];
  short8 o;
  o[0]=f2bf(v0[0]); o[1]=f2bf(v0[1]); o[2]=f2bf(v0[2]); o[3]=f2bf(v0[3]);
  o[4]=f2bf(v1[0]); o[5]=f2bf(v1[1]); o[6]=f2bf(v1[2]); o[7]=f2bf(v1[3]);
  *(short8*)(xbf + (((size_t)(s * 64 + b)) << 10) + d) = o;
}

template <bool XBF>
__global__ __launch_bounds__(1024, 4) void lstm_persist(
    const float* __restrict__ x, const short* __restrict__ xbf,
    const float* __restrict__ Wx, const float* __restrict__ bx,
    const float* __restrict__ Wh, const float* __restrict__ bh,
    float* __restrict__ out, unsigned* slots, short* hbuf, char* probe)
{
  __shared__ short hS[32 * 1024];      // 64 KB staged h, XOR-swizzled rows of 2 KB
  __shared__ float red[4][32][68];     // 34.8 KB [kq][batch][n], +4 pad
  __shared__ unsigned arrive;          // epi-wave arrival counter (monotonic)
  __shared__ unsigned flag;            // release fanout (epoch)

  const int tid  = threadIdx.x;
  const int bid  = blockIdx.x;
  const int g    = bid & 1;        // batch group
  const int js   = bid >> 1;       // j-slice 0..63
  const int lane = tid & 63;
  const int w    = tid >> 6;       // wave 0..15
  const int kq   = w >> 2;         // K-quarter: 0,1 -> x, 2,3 -> h
  const int rg   = w & 3;          // row-group (16 rows each)
  const int l15  = lane & 15;
  const int lh   = lane >> 4;

  unsigned* slot_g = slots + g * 1024;            // 64 slots x 64B line each
  short* hb_g = hbuf + (size_t)g * 65536;         // 2 x 32 x 1024 bf16 ring

  // ---- static weights: 16 rows per wave, n = l15 = jj*4+gi ----
  short8 bw[16];
  {
    const int gi  = l15 & 3;
    const int jj  = l15 >> 2;
    const int row = gi * 1024 + js * 16 + rg * 4 + jj;
    const float* Wsrc = (kq < 2) ? (Wx + (size_t)row * 1024 + kq * 512)
                                 : (Wh + (size_t)row * 1024 + (kq - 2) * 512);
    #pragma unroll
    for (int ks = 0; ks < 16; ++ks) {
      const float* p = Wsrc + ks * 32 + lh * 8;
      float4v v0 = *(const float4v*)p;
      float4v v1 = *(const float4v*)(p + 4);
      short8 o;
      o[0]=f2bf(v0[0]); o[1]=f2bf(v0[1]); o[2]=f2bf(v0[2]); o[3]=f2bf(v0[3]);
      o[4]=f2bf(v1[0]); o[5]=f2bf(v1[1]); o[6]=f2bf(v1[2]); o[7]=f2bf(v1[3]);
      bw[ks] = o;
    }
  }

  // ---- epilogue identity: tid<512 owns (batch eb, hidden ejj) ----
  const int eb  = tid >> 4;        // 0..31 (block-local batch)
  const int ejj = tid & 15;        // 0..15 (block-local j)
  const int jg  = js * 16 + ejj;   // global j
  float bias[4] = {0.f, 0.f, 0.f, 0.f};
  if (tid < 512) {
    #pragma unroll
    for (int gi = 0; gi < 4; ++gi) bias[gi] = bx[gi * 1024 + jg] + bh[gi * 1024 + jg];
  }
  float c_reg = 0.0f, h_keep = 0.0f;

  if (tid == 0) {
    __hip_atomic_store(&arrive, 0u, __ATOMIC_RELAXED, __HIP_MEMORY_SCOPE_WORKGROUP);
    __hip_atomic_store(&flag,   0u, __ATOMIC_RELAXED, __HIP_MEMORY_SCOPE_WORKGROUP);
  }
  __syncthreads();

  char* const hSB = (char*)hS;

  float bacc[4] = {0.1f, 0.2f, 0.3f, 0.4f};   // burn accumulators
  u64 wait_acc = 0;
  const bool meas = (bid == 0) && (w == 8);
  u64 tbeg = 0;
  if (meas) tbeg = memtime();

  for (int t = 0; t < 512; ++t) {
    float4v acc[2];
    acc[0] = (float4v){0.f, 0.f, 0.f, 0.f};
    acc[1] = (float4v){0.f, 0.f, 0.f, 0.f};

    if (kq < 2) {
      // ---- P1 (x-waves): x MFMAs, no h dependency ----
      if (XBF) {
        const short* xb = xbf + ((size_t)t << 16) + kq * 512 + lh * 8;
        #pragma unroll
        for (int ks = 0; ks < 16; ++ks) {
          #pragma unroll
          for (int mt = 0; mt < 2; ++mt) {
            const int b = g * 32 + mt * 16 + l15;
            short8 a = *(const short8*)(xb + ((size_t)b << 10) + ks * 32);
            acc[mt] = __builtin_amdgcn_mfma_f32_16x16x32_bf16(a, bw[ks], acc[mt], 0, 0, 0);
          }
        }
      } else {
        const float* Ab = x + (size_t)t * 1024 + kq * 512 + lh * 8;
        #pragma unroll
        for (int ks = 0; ks < 16; ++ks) {
          #pragma unroll
          for (int mt = 0; mt < 2; ++mt) {
            const int b = g * 32 + mt * 16 + l15;
            const float* p = Ab + (size_t)b * 524288 + ks * 32;
            float4v v0 = *(const float4v*)p;
            float4v v1 = *(const float4v*)(p + 4);
            short8 a;
            a[0]=f2bf(v0[0]); a[1]=f2bf(v0[1]); a[2]=f2bf(v0[2]); a[3]=f2bf(v0[3]);
            a[4]=f2bf(v1[0]); a[5]=f2bf(v1[1]); a[6]=f2bf(v1[2]); a[7]=f2bf(v1[3]);
            acc[mt] = __builtin_amdgcn_mfma_f32_16x16x32_bf16(a, bw[ks], acc[mt], 0, 0, 0);
          }
        }
      }
      #pragma unroll
      for (int mt = 0; mt < 2; ++mt)
        #pragma unroll
        for (int r = 0; r < 4; ++r)
          red[kq][mt * 16 + lh * 4 + r][rg * 16 + l15] = acc[mt][r];
    } else {
      // ---- P1 (h-waves): w8 polls slots (burning); w9-15 spin flag (burning) ----
      const unsigned target = (unsigned)t;
      if (w == 8) {
        u64 t0 = 0;
        if (meas) t0 = memtime();
        const unsigned* sp = slot_g + (size_t)lane * 16;   // one slot / 64B line
        for (;;) {
          const unsigned v = __hip_atomic_load(sp, __ATOMIC_RELAXED, __HIP_MEMORY_SCOPE_AGENT);
          if (__ballot(v >= target) == ~0ull) break;
          burn(bacc);
        }
        if (meas) wait_acc += memtime() - t0;
        if (lane == 0)
          __hip_atomic_store(&flag, (unsigned)(t + 1),
                             __ATOMIC_RELAXED, __HIP_MEMORY_SCOPE_WORKGROUP);
      } else {
        while (__hip_atomic_load(&flag, __ATOMIC_RELAXED, __HIP_MEMORY_SCOPE_WORKGROUP)
               < (unsigned)(t + 1)) {
          burn(bacc);
        }
      }
      // bulk stage 64 KB with 512 threads: 8 pipelined 16B loads each
      __builtin_amdgcn_s_setprio(1);
      const int tau = tid - 512;
      const int row = tau >> 4;          // 0..31
      const int sec = tau & 15;          // 0..15
      const short* src = hb_g + (size_t)(t & 1) * 32768 + row * 1024 + sec * 8;
      #pragma unroll
      for (int i = 0; i < 8; ++i) {
        const u64* p = (const u64*)(src + i * 128);
        union { u64 q[2]; short8 s; } u;
        u.q[0] = __hip_atomic_load(p,     __ATOMIC_RELAXED, __HIP_MEMORY_SCOPE_AGENT);
        u.q[1] = __hip_atomic_load(p + 1, __ATOMIC_RELAXED, __HIP_MEMORY_SCOPE_AGENT);
        const unsigned byte = (((unsigned)row << 11) + sec * 16 + i * 256)
                              ^ ((unsigned)(row & 7) << 4);
        *(short8*)(hSB + byte) = u.s;
      }
      __builtin_amdgcn_s_setprio(0);
    }
    __syncthreads();   // B1: h staged (x partials already in red)

    if (kq >= 2) {
      // ---- P2 (h-waves): swizzled ds_read_b128 frags + MFMA ----
      __builtin_amdgcn_s_setprio(1);
      const unsigned cb = (unsigned)((kq - 2) * 1024 + lh * 16);
      const unsigned xr = (unsigned)((l15 & 7) << 4);
      #pragma unroll
      for (int ks = 0; ks < 16; ++ks) {
        #pragma unroll
        for (int mt = 0; mt < 2; ++mt) {
          const unsigned byte = (((unsigned)(mt * 16 + l15) << 11) + cb + ks * 64) ^ xr;
          short8 a = *(const short8*)(hSB + byte);
          acc[mt] = __builtin_amdgcn_mfma_f32_16x16x32_bf16(a, bw[ks], acc[mt], 0, 0, 0);
        }
      }
      #pragma unroll
      for (int mt = 0; mt < 2; ++mt)
        #pragma unroll
        for (int r = 0; r < 4; ++r)
          red[kq][mt * 16 + lh * 4 + r][rg * 16 + l15] = acc[mt][r];
      __builtin_amdgcn_s_setprio(0);
    }
    __syncthreads();   // B2: all partials in red

    if (tid < 512) {
      // ---- P3 (epi waves 0-7): reduce + gates + ring store + arrive ----
      const int base = (ejj >> 2) * 16 + (ejj & 3) * 4;
      const float4v r0 = *(const float4v*)&red[0][eb][base];
      const float4v r1 = *(const float4v*)&red[1][eb][base];
      const float4v r2 = *(const float4v*)&red[2][eb][base];
      const float4v r3 = *(const float4v*)&red[3][eb][base];
      const float s0 = r0[0] + r1[0] + r2[0] + r3[0] + bias[0];
      const float s1 = r0[1] + r1[1] + r2[1] + r3[1] + bias[1];
      const float s2 = r0[2] + r1[2] + r2[2] + r3[2] + bias[2];
      const float s3 = r0[3] + r1[3] + r2[3] + r3[3] + bias[3];
      const float ig = sigm(s0);
      const float fg = sigm(s1);
      const float og = sigm(s2);
      const float gg = tanh_s(s3);
      c_reg = fg * c_reg + ig * gg;
      const float hh = og * tanh_s(c_reg);
      h_keep = hh;
      // ring store (pack 2 bf16 via shfl -> one u32 sc1 store)
      unsigned hv = (unsigned)(unsigned short)f2bf(hh);
      unsigned nb = (unsigned)__shfl_xor((int)hv, 1, 64);
      if ((ejj & 1) == 0) {
        unsigned vv = hv | (nb << 16);
        unsigned* dst = (unsigned*)(hb_g + (size_t)((t + 1) & 1) * 32768 + eb * 1024 + jg);
        __hip_atomic_store(dst, vv, __ATOMIC_RELAXED, __HIP_MEMORY_SCOPE_AGENT);
      }
      // drain the ring store ONLY, then register arrival locally (LDS).
      asm volatile("s_waitcnt vmcnt(0)" ::: "memory");
      if (lane == 0)
        __hip_atomic_fetch_add(&arrive, 1u, __ATOMIC_RELAXED, __HIP_MEMORY_SCOPE_WORKGROUP);
      // out store AFTER the arrival: fire-and-forget, drains at next B1.
      out[((size_t)(g * 32 + eb) * 512 + t) * 1024 + jg] = hh;
    } else if (w == 15) {
      // ---- block signaler: burn-spin on LDS counter, then slot store ----
      const unsigned tgt = 8u * (unsigned)(t + 1);
      while (__hip_atomic_load(&arrive, __ATOMIC_RELAXED, __HIP_MEMORY_SCOPE_WORKGROUP) < tgt) {
        burn(bacc);
      }
      if (lane == 0)
        __hip_atomic_store(slot_g + (size_t)js * 16, (unsigned)(t + 1),
                           __ATOMIC_RELAXED, __HIP_MEMORY_SCOPE_AGENT);
    }
    // no B3: red/hS reuse is ordered by B1/B2 + slot/flag-wait (see header)
  }

  if (tid < 512) {
    const size_t BSH = (size_t)64 * 512 * 1024;
    out[BSH + (size_t)(g * 32 + eb) * 1024 + jg] = h_keep;
    out[BSH + 65536 + (size_t)(g * 32 + eb) * 1024 + jg] = c_reg;
  }

  // keep burn accumulators live (no DCE of spin bodies)
  asm volatile("" :: "v"(bacc[0]), "v"(bacc[1]), "v"(bacc[2]), "v"(bacc[3]));

  // ---- WRITE_SIZE probe: 2MB marker + 0.25MB per 1/64 of wait fraction ----
  if (probe && meas) {
    const u64 total = memtime() - tbeg;
    unsigned units = total ? (unsigned)((wait_acc * 64ull) / total) : 0u;
    if (units > 64u) units = 64u;
    const int nlines = 32768 + (int)units * 4096;   // 64B lines
    int4v z; z[0] = 0; z[1] = 0; z[2] = 0; z[3] = 0;
    for (int i = lane; i < nlines; i += 64) {
      u64 p = (u64)(uintptr_t)(probe + (size_t)i * 64);
      asm volatile("global_store_dwordx4 %0, %1, off sc0 sc1 nt" :: "v"(p), "v"(z) : "memory");
      asm volatile("global_store_dwordx4 %0, %1, off offset:16 sc0 sc1 nt" :: "v"(p), "v"(z) : "memory");
      asm volatile("global_store_dwordx4 %0, %1, off offset:32 sc0 sc1 nt" :: "v"(p), "v"(z) : "memory");
      asm volatile("global_store_dwordx4 %0, %1, off offset:48 sc0 sc1 nt" :: "v"(p), "v"(z) : "memory");
    }
  }
}

extern "C" void kernel_launch(void* const* d_in, const int* in_sizes, int n_in,
                              void* d_out, int out_size, void* d_ws, size_t ws_size,
                              hipStream_t stream) {
  (void)in_sizes; (void)n_in; (void)out_size;
  const float* x  = (const float*)d_in[0];
  const float* Wx = (const float*)d_in[1];
  const float* bx = (const float*)d_in[2];
  const float* Wh = (const float*)d_in[3];
  const float* bh = (const float*)d_in[4];
  float* out = (float*)d_out;

  unsigned* slots = (unsigned*)d_ws;                        // 8 KB: 2 x 64 slots, 64B apart
  short* hbuf     = (short*)((char*)d_ws + 8192);           // 2 groups x 2 x 64 KB h ring
  short* xbf      = (short*)((char*)d_ws + 8192 + 262144);  // 64 MB bf16 x [t][b][d]
  const size_t need_xbf = 8192u + 262144u + (size_t)64 * 512 * 1024 * 2;
  const size_t need_probe = need_xbf + (size_t)20 * 1024 * 1024;

  char* probe = (ws_size >= need_probe) ? ((char*)d_ws + need_xbf) : nullptr;

  hipMemsetAsync(d_ws, 0, 8192 + 262144, stream);           // slots + h0 = 0

  if (ws_size >= need_xbf) {
    hipLaunchKernelGGL(xconv, dim3(16384), dim3(256), 0, stream, x, xbf);
    hipLaunchKernelGGL(lstm_persist<true>, dim3(128), dim3(1024), 0, stream,
                       x, xbf, Wx, bx, Wh, bh, out, slots, hbuf, probe);
  } else {
    hipLaunchKernelGGL(lstm_persist<false>, dim3(128), dim3(1024), 0, stream,
                       x, hbuf, Wx, bx, Wh, bh, out, slots, hbuf, nullptr);
  }
}